// Round 15
// baseline (181.475 us; speedup 1.0000x reference)
//
#include <hip/hip_runtime.h>
#include <math.h>

#define NB   16
#define NN   307
#define MPAD 308          // padded m for G rows
#define Q4   77           // MPAD/4: m-tiles of 4
#define KCH  3
#define IND  66           // INPUT_DIM + HIDDEN
#define KI   198          // KCH * IND
#define HID  64
#define HG   128          // 2 * HIDDEN

typedef float f32x4 __attribute__((ext_vector_type(4)));

// ws layout (floats)
#define OFF_GP   0
#define SZ_GP    (KCH * NN * MPAD)        // 283,668
#define OFF_X1   (OFF_GP + SZ_GP)
#define SZ_X     (NB * Q4 * IND * 4)      // 325,248  x tiled: [b][q][i][e], m = 4q+e
#define OFF_X2   (OFF_X1 + SZ_X)
#define OFF_Z    (OFF_X2 + SZ_X)
#define SZ_Z     (NB * NN * HID)
#define OFF_SUP  (OFF_Z + SZ_Z)           // sup: NB*NN*KI
#define SZ_X2I   (NB * Q4 * 2 * 4)        // x2 xt-row init elements (i<2 only)

__global__ void prep_kernel(const float* __restrict__ G,
                            const float* __restrict__ xt,
                            const float* __restrict__ h,
                            float* __restrict__ G_p,
                            float* __restrict__ x1,
                            float* __restrict__ x2) {
    int idx = blockIdx.x * blockDim.x + threadIdx.x;
    if (idx < SZ_GP) {
        int mp = idx % MPAD;
        int kn = idx / MPAD;
        G_p[idx] = (mp < NN) ? G[kn * NN + mp] : 0.f;
    } else if (idx < SZ_GP + SZ_X) {
        int j = idx - SZ_GP;
        int e = j & 3;
        int t = j >> 2;
        int i = t % IND;
        int q = (t / IND) % Q4;
        int b = t / (IND * Q4);
        int m = q * 4 + e;
        float v = 0.f;
        if (m < NN)
            v = (i < 2) ? xt[(b * NN + m) * 2 + i]
                        : h[(b * NN + m) * HID + (i - 2)];
        x1[j] = v;
    } else if (idx < SZ_GP + SZ_X + SZ_X2I) {
        int j = idx - SZ_GP - SZ_X;
        int e  = j & 3;
        int t  = j >> 2;
        int i  = t & 1;
        int t2 = t >> 1;
        int q  = t2 % Q4;
        int b  = t2 / Q4;
        int m  = q * 4 + e;
        float v = (m < NN) ? xt[(b * NN + m) * 2 + i] : 0.f;
        x2[(((size_t)b * Q4 + q) * IND + i) * 4 + e] = v;
    }
}

// Standalone gcn: exactly R7's phase-1, no concurrent W stream.
// sup[bn][k*66+i] = sum_m G[k][n][m] * x[b][m][i]
__global__ __launch_bounds__(128) void gcn_kernel(const float* __restrict__ G_p,
                                                  const float* __restrict__ xT,
                                                  float* __restrict__ sup) {
    const int bn  = blockIdx.x;
    const int b   = bn / NN;
    const int n   = bn % NN;
    const int tid = threadIdx.x;
    if (tid < IND) {
        const f32x4* xp = (const f32x4*)xT + (size_t)b * (Q4 * IND) + tid;
        const f32x4* gp = (const f32x4*)G_p + (size_t)n * Q4;
        f32x4 a0 = {0.f, 0.f, 0.f, 0.f}, a1 = a0, a2 = a0;
        #pragma unroll 7
        for (int q = 0; q < Q4; ++q) {
            f32x4 xv = xp[(size_t)q * IND];       // coalesced across lanes
            a0 += xv * gp[q];                      // wave-uniform broadcasts
            a1 += xv * gp[q + (size_t)NN * Q4];
            a2 += xv * gp[q + (size_t)2 * NN * Q4];
        }
        float* sp = sup + (size_t)bn * KI;
        sp[tid]           = a0.x + a0.y + a0.z + a0.w;
        sp[IND + tid]     = a1.x + a1.y + a1.z + a1.w;
        sp[2 * IND + tid] = a2.x + a2.y + a2.z + a2.w;
    }
}

// K1: gate stream; sup read from ws.
__global__ __launch_bounds__(128) void gate_fused(const float* __restrict__ sup,
                                                  const float* __restrict__ W,
                                                  const float* __restrict__ bias,
                                                  const float* __restrict__ h,
                                                  float* __restrict__ z_out,
                                                  float* __restrict__ xT2) {
    __shared__ float s[KI];
    __shared__ float red[4][HG];
    const int bn  = blockIdx.x;
    const int b   = bn / NN;
    const int n   = bn % NN;
    const int tid = threadIdx.x;
    for (int t = tid; t < KI; t += 128) s[t] = sup[(size_t)bn * KI + t];
    __syncthreads();
    const int r  = tid >> 5;
    const int c4 = (tid & 31) * 4;
    const f32x4* Wp = (const f32x4*)(W + (size_t)bn * KI * HG + c4);
    float4 acc = make_float4(0.f, 0.f, 0.f, 0.f);
    #pragma unroll 8
    for (int i = r; i < KI; i += 4) {
        f32x4 w = __builtin_nontemporal_load(Wp + (size_t)i * (HG / 4));
        float sv = s[i];
        acc.x += sv * w.x; acc.y += sv * w.y;
        acc.z += sv * w.z; acc.w += sv * w.w;
    }
    red[r][c4 + 0] = acc.x; red[r][c4 + 1] = acc.y;
    red[r][c4 + 2] = acc.z; red[r][c4 + 3] = acc.w;
    __syncthreads();
    float a = bias[(size_t)bn * HG + tid] + red[0][tid] + red[1][tid] + red[2][tid] + red[3][tid];
    float g = 1.0f / (1.0f + expf(-a));
    if (tid < HID) {
        z_out[bn * HID + tid] = g;                    // z
    } else {
        int hh = tid - HID;                           // r gate -> candidate elem at m=n
        int q = n >> 2, e = n & 3;
        xT2[(((size_t)b * Q4 + q) * IND + 2 + hh) * 4 + e] = g * h[bn * HID + hh];
    }
}

// K2: update stream; sup read from ws.
__global__ __launch_bounds__(128) void update_fused(const float* __restrict__ sup,
                                                    const float* __restrict__ W,
                                                    const float* __restrict__ bias,
                                                    const float* __restrict__ z,
                                                    const float* __restrict__ h,
                                                    float* __restrict__ out) {
    __shared__ float s[KI];
    __shared__ float red[8][HID];
    const int bn  = blockIdx.x;
    const int tid = threadIdx.x;
    for (int t = tid; t < KI; t += 128) s[t] = sup[(size_t)bn * KI + t];
    __syncthreads();
    const int r  = tid >> 4;
    const int c4 = (tid & 15) * 4;
    const f32x4* Wp = (const f32x4*)(W + (size_t)bn * KI * HID + c4);
    float4 acc = make_float4(0.f, 0.f, 0.f, 0.f);
    #pragma unroll 8
    for (int i = r; i < KI; i += 8) {
        f32x4 w = __builtin_nontemporal_load(Wp + (size_t)i * (HID / 4));
        float sv = s[i];
        acc.x += sv * w.x; acc.y += sv * w.y;
        acc.z += sv * w.z; acc.w += sv * w.w;
    }
    red[r][c4 + 0] = acc.x; red[r][c4 + 1] = acc.y;
    red[r][c4 + 2] = acc.z; red[r][c4 + 3] = acc.w;
    __syncthreads();
    if (tid < HID) {
        float a = bias[(size_t)bn * HID + tid];
        #pragma unroll
        for (int rr = 0; rr < 8; ++rr) a += red[rr][tid];
        float nn = tanhf(a);
        float zz = z[bn * HID + tid];
        float hv = h[bn * HID + tid];
        out[bn * HID + tid] = zz * nn + (1.f - zz) * hv;
    }
}

extern "C" void kernel_launch(void* const* d_in, const int* in_sizes, int n_in,
                              void* d_out, int out_size, void* d_ws, size_t ws_size,
                              hipStream_t stream) {
    const float* G  = (const float*)d_in[0];
    const float* xt = (const float*)d_in[1];
    const float* h  = (const float*)d_in[2];
    const float* Wg = (const float*)d_in[3];
    const float* bg = (const float*)d_in[4];
    const float* Wu = (const float*)d_in[5];
    const float* bu = (const float*)d_in[6];
    float* out = (float*)d_out;

    float* ws   = (float*)d_ws;
    float* G_p  = ws + OFF_GP;
    float* x1   = ws + OFF_X1;
    float* x2   = ws + OFF_X2;
    float* z    = ws + OFF_Z;
    float* sup  = ws + OFF_SUP;

    const int totPrep = SZ_GP + SZ_X + SZ_X2I;
    prep_kernel<<<(totPrep + 255) / 256, 256, 0, stream>>>(G, xt, h, G_p, x1, x2);

    gcn_kernel<<<NB * NN, 128, 0, stream>>>(G_p, x1, sup);

    gate_fused<<<NB * NN, 128, 0, stream>>>(sup, Wg, bg, h, z, x2);

    gcn_kernel<<<NB * NN, 128, 0, stream>>>(G_p, x2, sup);

    update_fused<<<NB * NN, 128, 0, stream>>>(sup, Wu, bu, z, h, out);
}